// Round 5
// baseline (534.419 us; speedup 1.0000x reference)
//
#include <hip/hip_runtime.h>
#include <hip/hip_bf16.h>

// LSTM: B=512, T=512, I=128, H=50, O=10, fp32.
// R5: (1) lstm_rec dot guaranteed-fast: fdot2 builtin if present, else
// fmaf((float)h,(float)w,acc) which selects v_fma_mix_f32 (R4's fallback was
// unfused cvt+fma ≈ 900 cyc/step of VALU — matched measured VALUBusy).
// (2) hbuf double-buffered -> 1 barrier/step; dots split into 2 chains.
// (3) xproj epilogue through LDS -> fully coalesced dword stores (R4's 52
// scattered 2B stores/thread made xproj ~215 us vs ~50 us floor).

#define BB 512
#define TT 512
#define II 128
#define HH 50
#define GG 200   // 4*H

typedef _Float16 half2v __attribute__((ext_vector_type(2)));
typedef _Float16 half4v __attribute__((ext_vector_type(4)));
typedef _Float16 half8v __attribute__((ext_vector_type(8)));
typedef float float4v __attribute__((ext_vector_type(4)));

#if defined(__has_builtin)
#if __has_builtin(__builtin_amdgcn_fdot2)
#define HAVE_FDOT2 1
#endif
#endif

__device__ __forceinline__ float dot2f(half2v a, half2v b, float c) {
#ifdef HAVE_FDOT2
    return __builtin_amdgcn_fdot2(a, b, c, false);
#else
    // fpext+fma pattern -> v_fma_mix_f32 (no separate cvt)
    return fmaf((float)a[1], (float)b[1], fmaf((float)a[0], (float)b[0], c));
#endif
}

__device__ __forceinline__ float fsig(float x) {
    return 1.f / (1.f + __expf(-x));
}
__device__ __forceinline__ float ftanh(float x) {
    return 2.f * fsig(2.f * x) - 1.f;
}

// ---------------- Kernel 0: prep (once per launch) ----------------
// wfrags: W_ih as f16 MFMA B-fragments [nt 13][kc 4][lane 64][j 8]
// whh16:  W_hh rows padded to 56 f16   [g 200][56]
// biasv:  b_ih + b_hh                  [g 200]
__global__ __launch_bounds__(256) void prep_kernel(
    const float* __restrict__ W_ih, const float* __restrict__ W_hh,
    const float* __restrict__ b_ih, const float* __restrict__ b_hh,
    _Float16* __restrict__ wfrags, _Float16* __restrict__ whh16,
    float* __restrict__ biasv)
{
    int idx = blockIdx.x * 256 + threadIdx.x;
    if (idx < 3328) {                       // 13*4*64 fragment slots
        int lane = idx & 63, kc = (idx >> 6) & 3, nt = idx >> 8;
        int g = nt * 16 + (lane & 15);
        int k0 = kc * 32 + ((lane >> 4) & 3) * 8;
        half8v v;
        #pragma unroll
        for (int j = 0; j < 8; ++j)
            v[j] = (g < GG) ? (_Float16)W_ih[g * II + k0 + j] : (_Float16)0.f;
        *(half8v*)(wfrags + (size_t)idx * 8) = v;
    } else if (idx < 3328 + 2800) {         // 200 rows * 14 quads
        int r = idx - 3328;
        int g = r / 14, j4 = r % 14;
        #pragma unroll
        for (int j = 0; j < 4; ++j) {
            int hidx = j4 * 4 + j;
            whh16[g * 56 + hidx] = (hidx < HH) ? (_Float16)W_hh[g * HH + hidx]
                                               : (_Float16)0.f;
        }
    } else if (idx < 3328 + 2800 + GG) {
        int g = idx - 6128;
        biasv[g] = b_ih[g] + b_hh[g];
    }
}

// ---------------- Kernel 1: xproj via MFMA, f16 output, coalesced stores ----
#define EPIW 216   // half-stride per row in epilogue LDS (16B-aligned rows, banks spread)
__global__ __launch_bounds__(256) void xproj_mfma(
    const float* __restrict__ x, const _Float16* __restrict__ wfrags,
    _Float16* __restrict__ xp16, int t0)
{
    __shared__ __align__(16) _Float16 smem[64 * EPIW];  // 27.6 KB; also A-staging (16 KB)
    const int tid = threadIdx.x;
    const int row0 = blockIdx.x * 64;       // rows = tl*512 + b; 64 | 512
    const int tl = row0 >> 9;
    const int b0 = row0 & 511;
    const int t = t0 + tl;

    // --- Stage A into fragment order (first 8192 halfs of smem) ---
    #pragma unroll
    for (int it = 0; it < 8; ++it) {
        int d = it * 512 + tid * 2;
        int lane = (d >> 2) & 63, kc = (d >> 8) & 3, wr = d >> 10;
        int jd = d & 3;                      // 0 or 2
        int row = wr * 16 + (lane & 15);
        int k0 = kc * 32 + ((lane >> 4) & 3) * 8 + jd * 2;
        const float4 v = *(const float4*)(x + ((size_t)(b0 + row) * TT + t) * II + k0);
        half4v p = { (_Float16)v.x, (_Float16)v.y, (_Float16)v.z, (_Float16)v.w };
        *(half4v*)(smem + d * 2) = p;
    }
    __syncthreads();

    const int w = tid >> 6;
    const int l = tid & 63;

    // Load all A fragments to regs up front (16 VGPR) so smem can be reused.
    half8v areg[4];
    #pragma unroll
    for (int kc = 0; kc < 4; ++kc)
        areg[kc] = *(half8v*)(smem + (((w * 4 + kc) * 64) + l) * 8);

    float4v acc[13];
    #pragma unroll
    for (int nt = 0; nt < 13; ++nt) acc[nt] = (float4v){0.f, 0.f, 0.f, 0.f};

    #pragma unroll
    for (int kc = 0; kc < 4; ++kc) {
        #pragma unroll
        for (int nt = 0; nt < 13; ++nt) {
            half8v bf = *(const half8v*)(wfrags + (size_t)(((nt * 4 + kc) * 64) + l) * 8);
            acc[nt] = __builtin_amdgcn_mfma_f32_16x16x32_f16(areg[kc], bf, acc[nt], 0, 0, 0);
        }
    }
    __syncthreads();   // all A-frag reads done; smem reused for epilogue

    // --- Write C tile to LDS [row][g], row stride EPIW halfs ---
    const int colb = l & 15, rquad = l >> 4;
    #pragma unroll
    for (int nt = 0; nt < 13; ++nt) {
        int g = nt * 16 + colb;
        if (g < GG) {
            #pragma unroll
            for (int reg = 0; reg < 4; ++reg) {
                int row = w * 16 + rquad * 4 + reg;
                smem[row * EPIW + g] = (_Float16)acc[nt][reg];
            }
        }
    }
    __syncthreads();

    // --- Coalesced copy: 64 rows x 200 halfs = 6400 dwords contiguous out ---
    uint32_t* xpw = (uint32_t*)(xp16 + (size_t)row0 * GG);
    #pragma unroll
    for (int kkk = 0; kkk < 25; ++kkk) {
        int d = tid + kkk * 256;            // dword index, < 6400
        int row = d / 100;
        int off = d - row * 100;            // dword within row
        uint32_t v = *(const uint32_t*)(smem + row * EPIW + off * 2);
        xpw[d] = v;
    }
}

// ---------------- Kernel 2: recurrence ----------------
// Wave-per-batch; f16 weights in regs (112 VGPR); h double-buffered in LDS
// (1 barrier/step); 4-deep circular xp prefetch; 2 chains per gate.
__global__ __launch_bounds__(64, 1) void lstm_rec(
    const _Float16* __restrict__ xp16, const _Float16* __restrict__ whh16,
    const float* __restrict__ biasv,
    float* __restrict__ hs, float* __restrict__ cs, int Tc, int first)
{
    __shared__ __align__(16) _Float16 hbuf[2][64];
    const int b = blockIdx.x;
    const int k = threadIdx.x;
    const int kk = (k < HH) ? k : 0;

    half8v wr0[7], wr1[7], wr2[7], wr3[7];
    #pragma unroll
    for (int j = 0; j < 7; ++j) {
        wr0[j] = *(const half8v*)(whh16 + (size_t)(kk      ) * 56 + j * 8);
        wr1[j] = *(const half8v*)(whh16 + (size_t)(kk +  50) * 56 + j * 8);
        wr2[j] = *(const half8v*)(whh16 + (size_t)(kk + 100) * 56 + j * 8);
        wr3[j] = *(const half8v*)(whh16 + (size_t)(kk + 150) * 56 + j * 8);
    }
    const float bi = biasv[kk], bf2 = biasv[kk + 50],
                bg = biasv[kk + 100], bo = biasv[kk + 150];

    float c = (!first && k < HH) ? cs[b * HH + kk] : 0.f;
    hbuf[0][k] = (_Float16)0.f;
    hbuf[1][k] = (_Float16)0.f;
    if (!first && k < HH) hbuf[0][k] = (_Float16)hs[b * HH + k];
    __syncthreads();

    const _Float16* xpb = xp16 + (size_t)b * GG;
    const size_t tstr = (size_t)BB * GG;

    _Float16 pi[4], pf[4], pg[4], po[4];
    #pragma unroll
    for (int d = 0; d < 4; ++d) {
        int td = (d < Tc) ? d : (Tc - 1);
        const _Float16* xn = xpb + (size_t)td * tstr;
        pi[d] = xn[kk]; pf[d] = xn[kk + 50]; pg[d] = xn[kk + 100]; po[d] = xn[kk + 150];
    }

    float hlast = 0.f;
    #pragma unroll 4
    for (int t = 0; t < Tc; ++t) {
        const int s = t & 3;
        const int cur = t & 1;
        float aI0 = (float)pi[s] + bi,  aI1 = 0.f;
        float aF0 = (float)pf[s] + bf2, aF1 = 0.f;
        float aG0 = (float)pg[s] + bg,  aG1 = 0.f;
        float aO0 = (float)po[s] + bo,  aO1 = 0.f;

        // refill slot s for t+4
        {
            int tn = t + 4; if (tn >= Tc) tn = Tc - 1;
            const _Float16* xn = xpb + (size_t)tn * tstr;
            pi[s] = xn[kk]; pf[s] = xn[kk + 50];
            pg[s] = xn[kk + 100]; po[s] = xn[kk + 150];
        }

        half8v hv[7];
        #pragma unroll
        for (int j = 0; j < 7; ++j) hv[j] = *(half8v*)(hbuf[cur] + j * 8);

        #pragma unroll
        for (int j = 0; j < 7; ++j) {
            half2v* hp = (half2v*)&hv[j];
            #pragma unroll
            for (int q = 0; q < 4; ++q) {
                half2v hq = hp[q];
                if (((j * 4 + q) & 1) == 0) {
                    aI0 = dot2f(hq, ((half2v*)&wr0[j])[q], aI0);
                    aF0 = dot2f(hq, ((half2v*)&wr1[j])[q], aF0);
                    aG0 = dot2f(hq, ((half2v*)&wr2[j])[q], aG0);
                    aO0 = dot2f(hq, ((half2v*)&wr3[j])[q], aO0);
                } else {
                    aI1 = dot2f(hq, ((half2v*)&wr0[j])[q], aI1);
                    aF1 = dot2f(hq, ((half2v*)&wr1[j])[q], aF1);
                    aG1 = dot2f(hq, ((half2v*)&wr2[j])[q], aG1);
                    aO1 = dot2f(hq, ((half2v*)&wr3[j])[q], aO1);
                }
            }
        }
        float ii = fsig(aI0 + aI1), ff = fsig(aF0 + aF1);
        float gg = ftanh(aG0 + aG1), oo = fsig(aO0 + aO1);
        c = ff * c + ii * gg;
        float hn = oo * ftanh(c);
        if (k < HH) hbuf[cur ^ 1][k] = (_Float16)hn;   // write other buffer: no race
        __syncthreads();                               // single barrier per step
        hlast = hn;
    }
    if (k < HH) {
        hs[b * HH + k] = hlast;
        cs[b * HH + k] = c;
    }
}

// ---------------- Kernel 3: FC epilogue ----------------
__global__ __launch_bounds__(256) void fc_kernel(
    const float* __restrict__ hs, const float* __restrict__ W_fc,
    const float* __restrict__ b_fc, float* __restrict__ out)
{
    int idx = blockIdx.x * blockDim.x + threadIdx.x;   // 512*10
    if (idx < BB * 10) {
        int b = idx / 10, o = idx % 10;
        float a = b_fc[o];
        #pragma unroll
        for (int kx = 0; kx < HH; ++kx)
            a += hs[b * HH + kx] * W_fc[o * HH + kx];
        out[idx] = a;
    }
}

extern "C" void kernel_launch(void* const* d_in, const int* in_sizes, int n_in,
                              void* d_out, int out_size, void* d_ws, size_t ws_size,
                              hipStream_t stream)
{
    const float* x    = (const float*)d_in[0];
    const float* W_ih = (const float*)d_in[1];
    const float* W_hh = (const float*)d_in[2];
    const float* b_ih = (const float*)d_in[3];
    const float* b_hh = (const float*)d_in[4];
    const float* W_fc = (const float*)d_in[5];
    const float* b_fc = (const float*)d_in[6];
    float* out = (float*)d_out;
    char* wsb = (char*)d_ws;

    const size_t hs_b = (size_t)BB * HH * sizeof(float);        // 102400
    const size_t wfrags_b = (size_t)13 * 4 * 64 * 8 * 2;        // 53248
    const size_t whh_b = (size_t)GG * 56 * 2;                   // 22400
    const size_t bias_b = 1024;
    const size_t fixed_b = 2 * hs_b + wfrags_b + whh_b + bias_b;

    int Tc = TT;
    while (Tc > 1 && (size_t)BB * Tc * GG * 2 + fixed_b > ws_size)
        Tc >>= 1;

    _Float16* xp16 = (_Float16*)wsb;
    char* p = wsb + (size_t)BB * Tc * GG * 2;
    float* hsbuf = (float*)p;            p += hs_b;
    float* csbuf = (float*)p;            p += hs_b;
    _Float16* wfrags = (_Float16*)p;     p += wfrags_b;
    _Float16* whh16 = (_Float16*)p;      p += whh_b;
    float* biasv = (float*)p;

    prep_kernel<<<25, 256, 0, stream>>>(W_ih, W_hh, b_ih, b_hh, wfrags, whh16, biasv);

    const int nch = TT / Tc;
    for (int j = 0; j < nch; ++j) {
        xproj_mfma<<<(BB * Tc) / 64, 256, 0, stream>>>(x, wfrags, xp16, j * Tc);
        lstm_rec<<<BB, 64, 0, stream>>>(xp16, whh16, biasv, hsbuf, csbuf, Tc, j == 0);
    }
    fc_kernel<<<(BB * 10 + 255) / 256, 256, 0, stream>>>(hsbuf, W_fc, b_fc, out);
}